// Round 10
// baseline (26.492 us; speedup 1.0000x reference)
//
#include <hip/hip_runtime.h>

#define HH 1024
#define WW 1024
#define NA 64
#define NBLK 128            // persistent: 8 rows per block
#define NGRP 8              // arrival tree: 8 groups x 16 blocks
#define GSIZE (NBLK / NGRP)

// ws control region, 17 lines of 128 B:
//   wsi[0]           root counter
//   wsi[32*(1+g)]    group counter g   (g<8)
//   wsi[32*(9+q)]    flag q (q<8): 0 = not ready, else float bits of scale (>0)
// byte 2176..: float2 part[NBLK]
#define WS_CTRL_BYTES (128 * 17)

__global__ __launch_bounds__(256) void frp_one(
    const float4* __restrict__ field,
    const float4* __restrict__ signal,
    const int*   __restrict__ apos,       // [NA][2]
    const float* __restrict__ astr,       // [NA]
    const float* __restrict__ p_is,
    const float* __restrict__ p_gr,
    const float* __restrict__ p_lr,
    float4* __restrict__ out,
    unsigned* __restrict__ wsi,
    float2* __restrict__ part)
{
    __shared__ int    s_pj[2][NA];
    __shared__ int    s_rad[2][NA];
    __shared__ int    s_di2[2][NA];
    __shared__ float  s_coef[2][NA];
    __shared__ float  s_inv[2][NA];
    __shared__ int    s_nact[2];
    __shared__ float  s_part[2][4];
    __shared__ double s_red[2][4];
    __shared__ int    s_last;
    __shared__ unsigned s_bits;

    const float lr = *p_lr;
    const float gr = *p_gr;
    const float is = *p_is;

    const int t    = threadIdx.x;
    const int b    = blockIdx.x;
    const int row0 = b * 8;

    const int half = t >> 7;              // 0 or 1: which row of the pair
    const int tt   = t & 127;             // position within row
    const int col0 = tt << 3;             // 8 consecutive px per thread

    float4 ua0, ub0, ua1, ub1, ua2, ub2, ua3, ub3;   // u held in registers
    float sf = 0.f, su = 0.f;

#pragma unroll
    for (int p = 0; p < 4; ++p) {
        if (p > 0) __syncthreads();       // LDS reuse guard
        // ---- wave 0: compact active attractors for rows row0+2p, +1 ----
        if (t < NA) {
            float s  = astr[t];
            int   pi = apos[2 * t + 0];
            int   pj = apos[2 * t + 1];
            int   r  = (int)floorf(5.0f * s);
            float cf = lr * s;
            float iv = -0.125f / (s * s);
#pragma unroll
            for (int rr = 0; rr < 2; ++rr) {
                int di = (row0 + 2 * p + rr) - pi;
                bool active = (di >= -r && di <= r);
                unsigned long long mask = __ballot(active);
                int pos = __popcll(mask & ((1ull << t) - 1ull));
                if (active) {
                    s_pj[rr][pos]   = pj;
                    s_rad[rr][pos]  = r;
                    s_di2[rr][pos]  = di * di;
                    s_coef[rr][pos] = cf;
                    s_inv[rr][pos]  = iv;
                }
                if (t == 0) s_nact[rr] = __popcll(mask);
            }
        }
        __syncthreads();

        const int row = row0 + 2 * p + half;
        const int n   = s_nact[half];

        float c[8] = {0,0,0,0,0,0,0,0};
        for (int k = 0; k < n; ++k) {     // ~1.1 iterations on average
            int   pj  = s_pj[half][k];
            int   r   = s_rad[half][k];
            int   di2 = s_di2[half][k];
            float cf  = s_coef[half][k];
            float iv  = s_inv[half][k];
#pragma unroll
            for (int q = 0; q < 8; ++q) {
                int dj = col0 + q - pj;
                if (dj >= -r && dj <= r)
                    c[q] += cf * __expf(iv * (float)(di2 + dj * dj));
            }
        }

        const int idx = row * (WW / 4) + (tt << 1);
        float4 f0 = field[idx];
        float4 f1 = field[idx + 1];
        float4 g0 = signal[idx];
        float4 g1 = signal[idx + 1];

        float a[8];
#pragma unroll
        for (int q = 0; q < 8; ++q)
            a[q] = is / (1.0f + __expf(-(gr + c[q])));

        float4 u0, u1;
        u0.x = f0.x + (g0.x - f0.x) * a[0];
        u0.y = f0.y + (g0.y - f0.y) * a[1];
        u0.z = f0.z + (g0.z - f0.z) * a[2];
        u0.w = f0.w + (g0.w - f0.w) * a[3];
        u1.x = f1.x + (g1.x - f1.x) * a[4];
        u1.y = f1.y + (g1.y - f1.y) * a[5];
        u1.z = f1.z + (g1.z - f1.z) * a[6];
        u1.w = f1.w + (g1.w - f1.w) * a[7];

        if (p == 0) { ua0 = u0; ub0 = u1; }
        if (p == 1) { ua1 = u0; ub1 = u1; }
        if (p == 2) { ua2 = u0; ub2 = u1; }
        if (p == 3) { ua3 = u0; ub3 = u1; }

        sf += f0.x*f0.x + f0.y*f0.y + f0.z*f0.z + f0.w*f0.w
            + f1.x*f1.x + f1.y*f1.y + f1.z*f1.z + f1.w*f1.w;
        su += u0.x*u0.x + u0.y*u0.y + u0.z*u0.z + u0.w*u0.w
            + u1.x*u1.x + u1.y*u1.y + u1.z*u1.z + u1.w*u1.w;
    }

    // ---- block reduction of partials ----
#pragma unroll
    for (int off = 32; off > 0; off >>= 1) {
        sf += __shfl_down(sf, off, 64);
        su += __shfl_down(su, off, 64);
    }
    const int wave = t >> 6;
    if ((t & 63) == 0) {
        s_part[0][wave] = sf;
        s_part[1][wave] = su;
    }
    __syncthreads();

    // ---- arrival: publish partial, 2-level tree (16 per group, 8 groups) ----
    if (t == 0) {
        part[b] = make_float2(
            s_part[0][0] + s_part[0][1] + s_part[0][2] + s_part[0][3],
            s_part[1][0] + s_part[1][1] + s_part[1][2] + s_part[1][3]);
        __threadfence();                                   // release partial
        const int g = b >> 4;
        unsigned old = atomicAdd(&wsi[32 * (1 + g)], 1u);
        int last = 0;
        if (old == GSIZE - 1) {
            __threadfence();
            unsigned o2 = atomicAdd(&wsi[0], 1u);
            if (o2 == NGRP - 1) last = 1;                  // final arrival
        }
        s_last = last;
    }
    __syncthreads();

    if (s_last) {
        // ---- reducer: reduce 128 partials, broadcast scale to 8 flags ----
        __threadfence();                                   // acquire
        double df = 0.0, du = 0.0;
        if (t < NBLK) {
            unsigned long long pv = __hip_atomic_load(
                (const unsigned long long*)(part + t),
                __ATOMIC_RELAXED, __HIP_MEMORY_SCOPE_AGENT);
            float2 p2;
            __builtin_memcpy(&p2, &pv, 8);
            df = (double)p2.x;
            du = (double)p2.y;
        }
#pragma unroll
        for (int off = 32; off > 0; off >>= 1) {
            df += __shfl_down(df, off, 64);
            du += __shfl_down(du, off, 64);
        }
        if ((t & 63) == 0) { s_red[0][wave] = df; s_red[1][wave] = du; }
        __syncthreads();
        if (t == 0) {
            double tf = s_red[0][0] + s_red[0][1] + s_red[0][2] + s_red[0][3];
            double tu = s_red[1][0] + s_red[1][1] + s_red[1][2] + s_red[1][3];
            float scale = (tu > 0.0) ? (float)sqrt(tf / tu) : 1.0f;
            s_bits = __float_as_uint(scale);
        }
        __syncthreads();
        if (t < NGRP)
            __hip_atomic_store(&wsi[32 * (9 + t)], s_bits,
                               __ATOMIC_RELAXED, __HIP_MEMORY_SCOPE_AGENT);
    } else {
        // ---- poll own flag line: relaxed agent loads + sleep ramp ----
        if (t == 0) {
            const unsigned* fl = &wsi[32 * (9 + (b & 7))];
            unsigned v = __hip_atomic_load(fl, __ATOMIC_RELAXED,
                                           __HIP_MEMORY_SCOPE_AGENT);
            if (v == 0u) {
                __builtin_amdgcn_s_sleep(4);
                v = __hip_atomic_load(fl, __ATOMIC_RELAXED, __HIP_MEMORY_SCOPE_AGENT);
            }
            if (v == 0u) {
                __builtin_amdgcn_s_sleep(8);
                v = __hip_atomic_load(fl, __ATOMIC_RELAXED, __HIP_MEMORY_SCOPE_AGENT);
            }
            if (v == 0u) {
                __builtin_amdgcn_s_sleep(16);
                v = __hip_atomic_load(fl, __ATOMIC_RELAXED, __HIP_MEMORY_SCOPE_AGENT);
            }
            while (v == 0u) {
                __builtin_amdgcn_s_sleep(32);
                v = __hip_atomic_load(fl, __ATOMIC_RELAXED, __HIP_MEMORY_SCOPE_AGENT);
            }
            s_bits = v;
        }
        __syncthreads();
    }

    // ---- tail: scale registers, write out ----
    const float sc = __uint_as_float(s_bits);
#pragma unroll
    for (int p = 0; p < 4; ++p) {
        const int row = row0 + 2 * p + half;
        const int idx = row * (WW / 4) + (tt << 1);
        float4 u0 = (p == 0) ? ua0 : (p == 1) ? ua1 : (p == 2) ? ua2 : ua3;
        float4 u1 = (p == 0) ? ub0 : (p == 1) ? ub1 : (p == 2) ? ub2 : ub3;
        u0.x *= sc; u0.y *= sc; u0.z *= sc; u0.w *= sc;
        u1.x *= sc; u1.y *= sc; u1.z *= sc; u1.w *= sc;
        out[idx]     = u0;
        out[idx + 1] = u1;
    }
}

extern "C" void kernel_launch(void* const* d_in, const int* in_sizes, int n_in,
                              void* d_out, int out_size, void* d_ws, size_t ws_size,
                              hipStream_t stream) {
    const float4* field  = (const float4*)d_in[0];
    const float4* signal = (const float4*)d_in[1];
    const int*    apos   = (const int*)d_in[2];
    const float*  astr   = (const float*)d_in[3];
    const float*  p_is   = (const float*)d_in[4];
    const float*  p_gr   = (const float*)d_in[5];
    const float*  p_lr   = (const float*)d_in[6];

    unsigned* wsi  = (unsigned*)d_ws;
    float2*   part = (float2*)((char*)d_ws + WS_CTRL_BYTES);

    hipMemsetAsync(d_ws, 0, WS_CTRL_BYTES, stream);   // reset counters + flags

    frp_one<<<NBLK, 256, 0, stream>>>(
        field, signal, apos, astr, p_is, p_gr, p_lr,
        (float4*)d_out, wsi, part);
}